// Round 6
// baseline (445.001 us; speedup 1.0000x reference)
//
#include <hip/hip_runtime.h>
#include <hip/hip_fp16.h>
#include <math.h>

#define BATCH 2048
#define NFEAT 7
#define CARD 10000
#define CONCAT 256
#define P_HID 512

#define BM 128
#define BN 128
#define BK 64
#define KSPLIT 16
#define NTILES 640            // triangle-packed 64-wide K-tiles
#define TILES_PER_SPLIT 40    // 640 / 16
#define K_PAD (NTILES * 64)   // 40960

using half8   = __attribute__((ext_vector_type(8))) _Float16;
using floatx4 = __attribute__((ext_vector_type(4))) float;

// async global->LDS DMA, 16 B per lane; LDS dest = wave-uniform base + lane*16
__device__ __forceinline__ void dma16(const _Float16* g, _Float16* l) {
    __builtin_amdgcn_global_load_lds(
        (const __attribute__((address_space(1))) unsigned int*)g,
        (__attribute__((address_space(3))) unsigned int*)l,
        16, 0, 0);
}

// tile t -> (d, i0): pairs (i, i+d), i in [i0, i0+64), valid while i+d < 256.
// d-runs padded to 64: d<64 -> 4 tiles, <128 -> 3, <192 -> 2, else 1.
__device__ __forceinline__ void tile_decode(int t, int& d, int& i0) {
    if (t < 256)      { d = t >> 2;                          i0 = (t & 3) << 6; }
    else if (t < 448) { unsigned u = t - 256;
                        unsigned q3 = (u * 0xAAABu) >> 17;   // u/3, u<192
                        d = 64 + q3;                         i0 = (u - 3 * q3) << 6; }
    else if (t < 576) { unsigned u = t - 448; d = 128 + (u >> 1); i0 = (u & 1) << 6; }
    else              { d = 192 + (t - 576);                 i0 = 0; }
}

// ---------------------------------------------------------------------------
// Kernel 1: dense MLP + embedding gather + sparse MLPs -> concat (fp16).
// tokenizers == arange(CARD) -> gather index is the sparse value itself.
// ---------------------------------------------------------------------------
__global__ __launch_bounds__(256) void build_concat(
    const float* __restrict__ dense, const int* __restrict__ sparse,
    const float* __restrict__ emb,
    const float* __restrict__ dw1, const float* __restrict__ db1,
    const float* __restrict__ dw2, const float* __restrict__ db2,
    const float* __restrict__ sw1, const float* __restrict__ sb1,
    const float* __restrict__ sw2, const float* __restrict__ sb2,
    _Float16* __restrict__ cbf)
{
    __shared__ float smem[576];
    const int tid = threadIdx.x, wv = tid >> 6, t = tid & 63;
    const int b = blockIdx.x * 4 + wv;
    float* xs   = smem + wv * 13;
    float* bufA = smem + 64  + wv * 64;
    float* bufB = smem + 320 + wv * 64;

    if (t < 13) xs[t] = dense[b * 13 + t];
    __syncthreads();

    float h = db1[t];
#pragma unroll
    for (int d = 0; d < 13; ++d) h += xs[d] * dw1[d * 64 + t];
    bufA[t] = fmaxf(h, 0.f);
    __syncthreads();

    if (t < 32) {
        float o = db2[t];
#pragma unroll
        for (int k = 0; k < 64; ++k) o += bufA[k] * dw2[k * 32 + t];
        cbf[b * 256 + t] = (_Float16)o;
    }

    for (int f = 0; f < NFEAT; ++f) {
        __syncthreads();
        const int idx = sparse[b * NFEAT + f];
        bufB[t] = emb[((size_t)(f * CARD + idx)) * 64 + t];
        __syncthreads();
        float s = sb1[f * 64 + t];
#pragma unroll
        for (int e = 0; e < 64; ++e) s += bufB[e] * sw1[(f * 64 + e) * 64 + t];
        bufA[t] = fmaxf(s, 0.f);
        __syncthreads();
        if (t < 32) {
            float o = sb2[f * 32 + t];
#pragma unroll
            for (int k = 0; k < 64; ++k) o += bufA[k] * sw2[(f * 64 + k) * 32 + t];
            cbf[b * 256 + 32 + f * 32 + t] = (_Float16)o;
        }
    }
}

// ---------------------------------------------------------------------------
// Kernel 2: symmetrized B-prep. St[n][t*64+q] = W[i*256+j,n] + W[j*256+i,n]
// for pair (i,j)=(i0+q, i0+q+d) of tile t; 0 on the padded tail.
// Row indices: i*256+j = i*257+d ; j*256+i = i*257+256d.
// Grid: 640 tiles x 8 n-chunks = 5120 blocks.
// ---------------------------------------------------------------------------
__global__ __launch_bounds__(256) void prep_S(const float* __restrict__ pw1,
                                              _Float16* __restrict__ St)
{
    __shared__ float tile[64 * 65 + 8];   // stride 65 dw -> conflict-free
    const int bid = blockIdx.x;
    const int t = bid >> 3, nc = bid & 7;
    const int n0 = nc * 64;
    int d, i0;
    tile_decode(t, d, i0);
    const int V = 256 - d - i0;           // valid q count (>=1 by construction)

    const int c = threadIdx.x & 15, qq = threadIdx.x >> 4;   // float4 col, q-base
#pragma unroll
    for (int p = 0; p < 4; ++p) {
        const int q = qq + 16 * p;
        float4 s = {0.f, 0.f, 0.f, 0.f};
        if (q < V) {
            const size_t i = (size_t)(i0 + q);
            s = *(const float4*)(pw1 + (i * 257 + d) * P_HID + n0 + 4 * c);
            if (d > 0) {
                const float4 bv = *(const float4*)(pw1 + (i * 257 + 256 * (size_t)d) * P_HID + n0 + 4 * c);
                s.x += bv.x; s.y += bv.y; s.z += bv.z; s.w += bv.w;
            }
        }
        float* dst = &tile[q * 65 + 4 * c];
        dst[0] = s.x; dst[1] = s.y; dst[2] = s.z; dst[3] = s.w;
    }
    __syncthreads();

    const int e = threadIdx.x & 7, nn = threadIdx.x >> 3;    // k-chunk, n-row
#pragma unroll
    for (int p2 = 0; p2 < 2; ++p2) {
        const int n = nn + 32 * p2;
        half8 o;
#pragma unroll
        for (int q2 = 0; q2 < 8; ++q2)
            o[q2] = (_Float16)tile[(8 * e + q2) * 65 + n];
        *(half8*)(St + (size_t)(n0 + n) * K_PAD + (size_t)t * 64 + 8 * e) = o;
    }
}

// ---------------------------------------------------------------------------
// Kernel 3: hidden[b,n] = sum over packed pairs A[b,k] * St[n,k].
// fp16 GEMM M=2048 N=512 K=40960; A[b,q] = c[b,i0+q]*c[b,i0+q+d] per tile
// (shifted-window pk-mul). B via global_load_lds, XOR-swizzled LDS slots.
// ---------------------------------------------------------------------------
__global__ __launch_bounds__(256, 4) void bilinear_gemm(
    const _Float16* __restrict__ cbf, const _Float16* __restrict__ St,
    _Float16* __restrict__ hidpart)
{
    __shared__ _Float16 Al[BM][BK + 8];   // 144 B stride -> uniform banks
    __shared__ _Float16 Bl[BN][BK];       // packed 128 B rows, XOR-swizzled

    // XCD-aware decode: 16 m-blocks of one (nt,ks) slice share one XCD's L2.
    const int b = blockIdx.x;
    const int xcd = b & 7, slot = b >> 3;
    const int mt = slot & 15;
    const int slice = ((slot >> 4) << 3) | xcd;
    const int nt = slice & 3, ks = slice >> 2;
    const int m0 = mt * BM, n0 = nt * BN;
    const int t0 = ks * TILES_PER_SPLIT;

    const int tid = threadIdx.x, lane = tid & 63, wv = tid >> 6;
    const int wrow = (wv & 1) * 64, wcol = (wv >> 1) * 64;
    const int arow = tid >> 1, ajoff = (tid & 1) * 32;  // A-gen: 2 thr/row

    floatx4 acc[4][4];
#pragma unroll
    for (int i = 0; i < 4; ++i)
#pragma unroll
        for (int j = 0; j < 4; ++j) acc[i][j] = (floatx4){0.f, 0.f, 0.f, 0.f};

    const _Float16* crow = cbf + (m0 + arow) * 256;
    const int drow = wv * 32 + (lane >> 3);
    const int eswz = (lane & 7) ^ ((lane >> 3) & 7);
    const _Float16* bsrc = St + (size_t)(n0 + drow) * K_PAD + (size_t)t0 * 64 + eswz * 8;
    _Float16* bdst = &Bl[wv * 32][0];   // wave-uniform; HW adds lane*16B

    for (int it = 0; it < TILES_PER_SPLIT; ++it) {
        // ---- B stage: async DMA, 4 x 1KB issues per wave ----
#pragma unroll
        for (int p = 0; p < 4; ++p)
            dma16(bsrc + (size_t)(p * 8) * K_PAD, bdst + (p * 8) * BK);
        bsrc += BK;

        // ---- A-gen: shifted-window product (overlaps DMA) ----
        int d, i0;
        tile_decode(t0 + it, d, i0);
        const _Float16* p1 = crow + i0 + ajoff;         // 16B-aligned
        const _Float16* p2 = p1 + d;                    // 2B-aligned
#pragma unroll
        for (int x = 0; x < 32; x += 8) {
            half8 va = *(const half8*)(p1 + x);
            half8 vb;
            __builtin_memcpy(&vb, p2 + x, 16);          // unaligned-safe
            *(half8*)&Al[arow][ajoff + x] = va * vb;    // 4x v_pk_mul_f16
        }
        __syncthreads();   // drains vmcnt (DMA) + lgkm (A writes)

        // ---- MFMA: 2 k-steps of 32, 4x4 16x16 tiles per wave ----
#pragma unroll
        for (int kk = 0; kk < BK; kk += 32) {
            half8 af[4], bfr[4];
#pragma unroll
            for (int i = 0; i < 4; ++i)
                af[i] = *(const half8*)&Al[wrow + i * 16 + (lane & 15)][kk + (lane >> 4) * 8];
#pragma unroll
            for (int j = 0; j < 4; ++j) {
                const int s = (((kk >> 3) + (lane >> 4)) ^ (lane & 7)) * 8;
                bfr[j] = *(const half8*)&Bl[wcol + j * 16 + (lane & 15)][s];
            }
#pragma unroll
            for (int i = 0; i < 4; ++i)
#pragma unroll
                for (int j = 0; j < 4; ++j)
                    acc[i][j] = __builtin_amdgcn_mfma_f32_16x16x32_f16(
                        af[i], bfr[j], acc[i][j], 0, 0, 0);
        }
        __syncthreads();
    }

    // epilogue: C/D layout col=lane&15, row=(lane>>4)*4+r (m89-verified)
    _Float16* outp = hidpart + (size_t)ks * BATCH * P_HID;
    const int r0 = m0 + wrow + (lane >> 4) * 4;
    const int c0 = n0 + wcol + (lane & 15);
#pragma unroll
    for (int i = 0; i < 4; ++i)
#pragma unroll
        for (int j = 0; j < 4; ++j)
#pragma unroll
            for (int r = 0; r < 4; ++r)
                outp[(size_t)(r0 + i * 16 + r) * P_HID + c0 + j * 16] =
                    (_Float16)acc[i][j][r];
}

// ---------------------------------------------------------------------------
// Kernel 4: sum k-splits + pb1, ReLU, dot with pw2, +pb2, sigmoid -> f32 out
// ---------------------------------------------------------------------------
__global__ void finalize(const _Float16* __restrict__ hidpart,
                         const float* __restrict__ pb1,
                         const float* __restrict__ pw2,
                         const float* __restrict__ pb2,
                         float* __restrict__ out)
{
    const int b = blockIdx.x, t = threadIdx.x;  // 256 threads
    float accv = 0.f;
#pragma unroll
    for (int h = 0; h < 2; ++h) {
        const int n = t + h * 256;
        float v = 0.f;
#pragma unroll
        for (int s = 0; s < KSPLIT; ++s)
            v += (float)hidpart[(size_t)s * BATCH * P_HID + (size_t)b * P_HID + n];
        v += pb1[n];
        v = fmaxf(v, 0.f);
        accv += v * pw2[n];
    }
#pragma unroll
    for (int off = 32; off; off >>= 1) accv += __shfl_down(accv, off, 64);
    __shared__ float red[4];
    const int lane = t & 63, wv = t >> 6;
    if (lane == 0) red[wv] = accv;
    __syncthreads();
    if (t == 0) {
        const float s = red[0] + red[1] + red[2] + red[3] + pb2[0];
        out[b] = 1.f / (1.f + expf(-s));
    }
}

extern "C" void kernel_launch(void* const* d_in, const int* in_sizes, int n_in,
                              void* d_out, int out_size, void* d_ws, size_t ws_size,
                              hipStream_t stream)
{
    const float* dense  = (const float*)d_in[0];
    const int*   sparse = (const int*)d_in[1];
    // d_in[2] tokenizers == arange(CARD): gather index is the sparse value itself
    const float* emb = (const float*)d_in[3];
    const float* dw1 = (const float*)d_in[4];
    const float* db1 = (const float*)d_in[5];
    const float* dw2 = (const float*)d_in[6];
    const float* db2 = (const float*)d_in[7];
    const float* sw1 = (const float*)d_in[8];
    const float* sb1 = (const float*)d_in[9];
    const float* sw2 = (const float*)d_in[10];
    const float* sb2 = (const float*)d_in[11];
    const float* pw1 = (const float*)d_in[12];
    const float* pb1 = (const float*)d_in[13];
    const float* pw2 = (const float*)d_in[14];
    const float* pb2 = (const float*)d_in[15];

    char* ws = (char*)d_ws;
    _Float16* cbf     = (_Float16*)ws;                                   // 1 MB
    _Float16* St      = (_Float16*)(ws + (1 << 20));                     // 40 MB
    _Float16* hidpart = (_Float16*)(ws + (1 << 20) + ((size_t)40 << 20)); // 32 MB

    build_concat<<<BATCH / 4, 256, 0, stream>>>(dense, sparse, emb, dw1, db1,
                                                dw2, db2, sw1, sb1, sw2, sb2, cbf);
    prep_S<<<NTILES * 8, 256, 0, stream>>>(pw1, St);
    bilinear_gemm<<<16 * 4 * KSPLIT, 256, 0, stream>>>(cbf, St, hidpart);
    finalize<<<BATCH, 256, 0, stream>>>(hidpart, pb1, pw2, pb2, (float*)d_out);
}

// Round 7
// 391.821 us; speedup vs baseline: 1.1357x; 1.1357x over previous
//
#include <hip/hip_runtime.h>
#include <hip/hip_fp16.h>
#include <math.h>

#define BATCH 2048
#define NFEAT 7
#define CARD 10000
#define CONCAT 256
#define P_HID 512

#define BM 128
#define BN 128
#define BK 64
#define KSPLIT 16
#define NUNITS 640            // triangle-packed (i, j-window) units
#define TILES_PER_SPLIT 40    // 640 / 16
#define K_PAD (NUNITS * 64)   // 40960

using half8   = __attribute__((ext_vector_type(8))) _Float16;
using floatx4 = __attribute__((ext_vector_type(4))) float;

// async global->LDS DMA, 16 B per lane; LDS dest = wave-uniform base + lane*16
__device__ __forceinline__ void dma16(const _Float16* g, _Float16* l) {
    __builtin_amdgcn_global_load_lds(
        (const __attribute__((address_space(1))) unsigned int*)g,
        (__attribute__((address_space(3))) unsigned int*)l,
        16, 0, 0);
}

// unit u -> (i, jw): pairs (i, j) with j in [jw*64, jw*64+64).
// u<256: diagonal-window units, i=u, jw=i>>6 (entries j<i zeroed in B).
// u>=256: full units, ordered by i with jw > i>>6.
__device__ __forceinline__ void unit_decode(int u, int& i, int& jw) {
    if (u < 256)      { i = u;                jw = u >> 6; }
    else if (u < 448) { int v = u - 256; i = v / 3;        jw = 1 + v % 3; }
    else if (u < 576) { int v = u - 448; i = 64 + (v >> 1); jw = 2 + (v & 1); }
    else              { i = 128 + (u - 576); jw = 3; }
}

// ---------------------------------------------------------------------------
// Kernel 1: dense MLP + embedding gather + sparse MLPs -> concat (fp16).
// Shuffle-based: one wave per head, no LDS, no barriers. 8 heads / 4 waves.
// tokenizers == arange(CARD) -> gather index is the sparse value itself.
// ---------------------------------------------------------------------------
__global__ __launch_bounds__(256) void build_concat(
    const float* __restrict__ dense, const int* __restrict__ sparse,
    const float* __restrict__ emb,
    const float* __restrict__ dw1, const float* __restrict__ db1,
    const float* __restrict__ dw2, const float* __restrict__ db2,
    const float* __restrict__ sw1, const float* __restrict__ sb1,
    const float* __restrict__ sw2, const float* __restrict__ sb2,
    _Float16* __restrict__ cbf)
{
    const int tid = threadIdx.x, wv = tid >> 6, t = tid & 63;
    const int b = blockIdx.x;

    for (int un = wv; un < 8; un += 4) {
        if (un == 0) {
            // dense head: 13 -> 64 -> 32
            float x = (t < 13) ? dense[b * 13 + t] : 0.f;
            float h = db1[t];
#pragma unroll
            for (int d = 0; d < 13; ++d) h += __shfl(x, d, 64) * dw1[d * 64 + t];
            h = fmaxf(h, 0.f);
            float o = (t < 32) ? db2[t] : 0.f;
#pragma unroll
            for (int k = 0; k < 64; ++k) o += __shfl(h, k, 64) * dw2[k * 32 + (t & 31)];
            if (t < 32) cbf[b * 256 + t] = (_Float16)o;
        } else {
            const int f = un - 1;
            const int idx = sparse[b * NFEAT + f];
            float g = emb[((size_t)(f * CARD + idx)) * 64 + t];
            float s = sb1[f * 64 + t];
#pragma unroll
            for (int e = 0; e < 64; ++e) s += __shfl(g, e, 64) * sw1[(f * 64 + e) * 64 + t];
            s = fmaxf(s, 0.f);
            float o = (t < 32) ? sb2[f * 32 + t] : 0.f;
#pragma unroll
            for (int k = 0; k < 64; ++k) o += __shfl(s, k, 64) * sw2[(f * 64 + k) * 32 + (t & 31)];
            if (t < 32) cbf[b * 256 + 32 + f * 32 + t] = (_Float16)o;
        }
    }
}

// ---------------------------------------------------------------------------
// Kernel 2: symmetrized B-prep, unit scheme.
// St[n][u*64+q] for unit (i,jw), j=jw*64+q:
//   j <  i : 0                (only in diagonal-window units)
//   j == i : W[i*256+i][n]
//   j >  i : W[i*256+j][n] + W[j*256+i][n]
// Grid: 640 units x 8 n-chunks = 5120 blocks.
// ---------------------------------------------------------------------------
__global__ __launch_bounds__(256) void prep_S(const float* __restrict__ pw1,
                                              _Float16* __restrict__ St)
{
    __shared__ float tile[64 * 65 + 8];   // stride 65 dw -> conflict-free
    const int bid = blockIdx.x;
    const int u = bid >> 3, nc = bid & 7;
    const int n0 = nc * 64;
    int i, jw;
    unit_decode(u, i, jw);

    const int c = threadIdx.x & 15, qq = threadIdx.x >> 4;   // float4 col, q-base
#pragma unroll
    for (int p = 0; p < 4; ++p) {
        const int q = qq + 16 * p;
        const int j = (jw << 6) + q;
        float4 s = {0.f, 0.f, 0.f, 0.f};
        if (j >= i) {
            s = *(const float4*)(pw1 + ((size_t)i * 256 + j) * P_HID + n0 + 4 * c);
            if (j > i) {
                const float4 bv = *(const float4*)(pw1 + ((size_t)j * 256 + i) * P_HID + n0 + 4 * c);
                s.x += bv.x; s.y += bv.y; s.z += bv.z; s.w += bv.w;
            }
        }
        float* dst = &tile[q * 65 + 4 * c];
        dst[0] = s.x; dst[1] = s.y; dst[2] = s.z; dst[3] = s.w;
    }
    __syncthreads();

    const int e = threadIdx.x & 7, nn = threadIdx.x >> 3;    // k-chunk, n-row
#pragma unroll
    for (int p2 = 0; p2 < 2; ++p2) {
        const int n = nn + 32 * p2;
        half8 o;
#pragma unroll
        for (int q2 = 0; q2 < 8; ++q2)
            o[q2] = (_Float16)tile[(8 * e + q2) * 65 + n];
        *(half8*)(St + (size_t)(n0 + n) * K_PAD + (size_t)u * 64 + 8 * e) = o;
    }
}

// ---------------------------------------------------------------------------
// Kernel 3: hidden[b,n] = sum over packed pairs A[b,k] * St[n,k].
// fp16 GEMM M=2048 N=512 K=40960; A[b,q] = c[b,i] * c[b,jw*64+q] per unit —
// scalar broadcast x ALIGNED window (round-5 cost). B via global_load_lds,
// XOR-swizzled LDS slots.
// ---------------------------------------------------------------------------
__global__ __launch_bounds__(256, 4) void bilinear_gemm(
    const _Float16* __restrict__ cbf, const _Float16* __restrict__ St,
    _Float16* __restrict__ hidpart)
{
    __shared__ _Float16 Al[BM][BK + 8];   // 144 B stride -> uniform banks
    __shared__ _Float16 Bl[BN][BK];       // packed 128 B rows, XOR-swizzled

    // XCD-aware decode: 16 m-blocks of one (nt,ks) slice share one XCD's L2.
    const int b = blockIdx.x;
    const int xcd = b & 7, slot = b >> 3;
    const int mt = slot & 15;
    const int slice = ((slot >> 4) << 3) | xcd;
    const int nt = slice & 3, ks = slice >> 2;
    const int m0 = mt * BM, n0 = nt * BN;
    const int t0 = ks * TILES_PER_SPLIT;

    const int tid = threadIdx.x, lane = tid & 63, wv = tid >> 6;
    const int wrow = (wv & 1) * 64, wcol = (wv >> 1) * 64;
    const int arow = tid >> 1, ajoff = (tid & 1) * 32;  // A-gen: 2 thr/row

    floatx4 acc[4][4];
#pragma unroll
    for (int i = 0; i < 4; ++i)
#pragma unroll
        for (int j = 0; j < 4; ++j) acc[i][j] = (floatx4){0.f, 0.f, 0.f, 0.f};

    const _Float16* crow = cbf + (m0 + arow) * 256;
    const int drow = wv * 32 + (lane >> 3);
    const int eswz = (lane & 7) ^ ((lane >> 3) & 7);
    const _Float16* bsrc = St + (size_t)(n0 + drow) * K_PAD + (size_t)t0 * 64 + eswz * 8;
    _Float16* bdst = &Bl[wv * 32][0];   // wave-uniform; HW adds lane*16B

    for (int it = 0; it < TILES_PER_SPLIT; ++it) {
        // ---- B stage: async DMA, 4 x 1KB issues per wave ----
#pragma unroll
        for (int p = 0; p < 4; ++p)
            dma16(bsrc + (size_t)(p * 8) * K_PAD, bdst + (p * 8) * BK);
        bsrc += BK;

        // ---- A-gen: scalar x aligned window (overlaps DMA) ----
        int ui, ujw;
        unit_decode(t0 + it, ui, ujw);
        const _Float16 ci = crow[ui];
        const half8 civ = {ci, ci, ci, ci, ci, ci, ci, ci};
        const _Float16* cj = crow + (ujw << 6) + ajoff;   // 16B-aligned
#pragma unroll
        for (int x = 0; x < 32; x += 8) {
            half8 v = *(const half8*)(cj + x);
            *(half8*)&Al[arow][ajoff + x] = v * civ;      // 4x v_pk_mul_f16
        }
        __syncthreads();   // drains vmcnt (DMA) + lgkm (A writes)

        // ---- MFMA: 2 k-steps of 32, 4x4 16x16 tiles per wave ----
#pragma unroll
        for (int kk = 0; kk < BK; kk += 32) {
            half8 af[4], bfr[4];
#pragma unroll
            for (int i = 0; i < 4; ++i)
                af[i] = *(const half8*)&Al[wrow + i * 16 + (lane & 15)][kk + (lane >> 4) * 8];
#pragma unroll
            for (int j = 0; j < 4; ++j) {
                const int s = (((kk >> 3) + (lane >> 4)) ^ (lane & 7)) * 8;
                bfr[j] = *(const half8*)&Bl[wcol + j * 16 + (lane & 15)][s];
            }
#pragma unroll
            for (int i = 0; i < 4; ++i)
#pragma unroll
                for (int j = 0; j < 4; ++j)
                    acc[i][j] = __builtin_amdgcn_mfma_f32_16x16x32_f16(
                        af[i], bfr[j], acc[i][j], 0, 0, 0);
        }
        __syncthreads();
    }

    // epilogue: C/D layout col=lane&15, row=(lane>>4)*4+r (m89-verified)
    _Float16* outp = hidpart + (size_t)ks * BATCH * P_HID;
    const int r0 = m0 + wrow + (lane >> 4) * 4;
    const int c0 = n0 + wcol + (lane & 15);
#pragma unroll
    for (int i = 0; i < 4; ++i)
#pragma unroll
        for (int j = 0; j < 4; ++j)
#pragma unroll
            for (int r = 0; r < 4; ++r)
                outp[(size_t)(r0 + i * 16 + r) * P_HID + c0 + j * 16] =
                    (_Float16)acc[i][j][r];
}

// ---------------------------------------------------------------------------
// Kernel 4: sum k-splits + pb1, ReLU, dot with pw2, +pb2, sigmoid -> f32 out
// ---------------------------------------------------------------------------
__global__ void finalize(const _Float16* __restrict__ hidpart,
                         const float* __restrict__ pb1,
                         const float* __restrict__ pw2,
                         const float* __restrict__ pb2,
                         float* __restrict__ out)
{
    const int b = blockIdx.x, t = threadIdx.x;  // 256 threads
    float accv = 0.f;
#pragma unroll
    for (int h = 0; h < 2; ++h) {
        const int n = t + h * 256;
        float v = 0.f;
#pragma unroll
        for (int s = 0; s < KSPLIT; ++s)
            v += (float)hidpart[(size_t)s * BATCH * P_HID + (size_t)b * P_HID + n];
        v += pb1[n];
        v = fmaxf(v, 0.f);
        accv += v * pw2[n];
    }
#pragma unroll
    for (int off = 32; off; off >>= 1) accv += __shfl_down(accv, off, 64);
    __shared__ float red[4];
    const int lane = t & 63, wv = t >> 6;
    if (lane == 0) red[wv] = accv;
    __syncthreads();
    if (t == 0) {
        const float s = red[0] + red[1] + red[2] + red[3] + pb2[0];
        out[b] = 1.f / (1.f + expf(-s));
    }
}

extern "C" void kernel_launch(void* const* d_in, const int* in_sizes, int n_in,
                              void* d_out, int out_size, void* d_ws, size_t ws_size,
                              hipStream_t stream)
{
    const float* dense  = (const float*)d_in[0];
    const int*   sparse = (const int*)d_in[1];
    // d_in[2] tokenizers == arange(CARD): gather index is the sparse value itself
    const float* emb = (const float*)d_in[3];
    const float* dw1 = (const float*)d_in[4];
    const float* db1 = (const float*)d_in[5];
    const float* dw2 = (const float*)d_in[6];
    const float* db2 = (const float*)d_in[7];
    const float* sw1 = (const float*)d_in[8];
    const float* sb1 = (const float*)d_in[9];
    const float* sw2 = (const float*)d_in[10];
    const float* sb2 = (const float*)d_in[11];
    const float* pw1 = (const float*)d_in[12];
    const float* pb1 = (const float*)d_in[13];
    const float* pw2 = (const float*)d_in[14];
    const float* pb2 = (const float*)d_in[15];

    char* ws = (char*)d_ws;
    _Float16* cbf     = (_Float16*)ws;                                   // 1 MB
    _Float16* St      = (_Float16*)(ws + (1 << 20));                     // 40 MB
    _Float16* hidpart = (_Float16*)(ws + (1 << 20) + ((size_t)40 << 20)); // 32 MB

    build_concat<<<BATCH, 256, 0, stream>>>(dense, sparse, emb, dw1, db1,
                                            dw2, db2, sw1, sb1, sw2, sb2, cbf);
    prep_S<<<NUNITS * 8, 256, 0, stream>>>(pw1, St);
    bilinear_gemm<<<16 * 4 * KSPLIT, 256, 0, stream>>>(cbf, St, hidpart);
    finalize<<<BATCH, 256, 0, stream>>>(hidpart, pb1, pw2, pb2, (float*)d_out);
}

// Round 8
// 383.269 us; speedup vs baseline: 1.1611x; 1.0223x over previous
//
#include <hip/hip_runtime.h>
#include <hip/hip_fp16.h>
#include <math.h>

#define BATCH 2048
#define NFEAT 7
#define CARD 10000
#define CONCAT 256
#define P_HID 512

#define BM 128
#define BN 128
#define BK 64
#define KSPLIT 16
#define NUNITS 640            // triangle-packed (i, j-window) units
#define TILES_PER_SPLIT 40    // 640 / 16
#define K_PAD (NUNITS * 64)   // 40960
#define PREP_BLOCKS (NUNITS * 8)

using half8   = __attribute__((ext_vector_type(8))) _Float16;
using floatx4 = __attribute__((ext_vector_type(4))) float;

// async global->LDS DMA, 16 B per lane; LDS dest = wave-uniform base + lane*16
__device__ __forceinline__ void dma16(const _Float16* g, _Float16* l) {
    __builtin_amdgcn_global_load_lds(
        (const __attribute__((address_space(1))) unsigned int*)g,
        (__attribute__((address_space(3))) unsigned int*)l,
        16, 0, 0);
}

// unit u -> (i, jw): pairs (i, j) with j in [jw*64, jw*64+64).
// u<256: diagonal-window units, i=u, jw=i>>6 (entries j<i zeroed in B).
// u>=256: full units, ordered by i with jw > i>>6.
__device__ __forceinline__ void unit_decode(int u, int& i, int& jw) {
    if (u < 256)      { i = u;                jw = u >> 6; }
    else if (u < 448) { int v = u - 256; i = v / 3;        jw = 1 + v % 3; }
    else if (u < 576) { int v = u - 448; i = 64 + (v >> 1); jw = 2 + (v & 1); }
    else              { i = 128 + (u - 576); jw = 3; }
}

// ---------------------------------------------------------------------------
// Kernel 1 (fused pre):
//  blockIdx <  PREP_BLOCKS: symmetrized B-prep (unit scheme).
//    St[n][u*64+q], j=jw*64+q: j<i -> 0 ; j==i -> W[i,i] ; j>i -> W[i,j]+W[j,i]
//    (reads every pw1 element exactly once: upper tri direct, lower tri mirror)
//  blockIdx >= PREP_BLOCKS: dense MLP + gather + sparse MLPs -> concat fp16,
//    4 batch rows per block (LDS version — faster than shuffle variant, R7).
//  tokenizers == arange(CARD) -> gather index is the sparse value itself.
// ---------------------------------------------------------------------------
__global__ __launch_bounds__(256) void fused_pre(
    const float* __restrict__ dense, const int* __restrict__ sparse,
    const float* __restrict__ emb,
    const float* __restrict__ dw1, const float* __restrict__ db1,
    const float* __restrict__ dw2, const float* __restrict__ db2,
    const float* __restrict__ sw1, const float* __restrict__ sb1,
    const float* __restrict__ sw2, const float* __restrict__ sb2,
    const float* __restrict__ pw1,
    _Float16* __restrict__ cbf, _Float16* __restrict__ St)
{
    __shared__ float smem[64 * 65 + 8];   // 16.7 KB; stride 65 -> conflict-free
    const int tid = threadIdx.x;

    if (blockIdx.x < PREP_BLOCKS) {
        const int u = blockIdx.x >> 3, nc = blockIdx.x & 7;
        const int n0 = nc * 64;
        int i, jw;
        unit_decode(u, i, jw);

        const int c = tid & 15, qq = tid >> 4;   // float4 col, q-base
#pragma unroll
        for (int p = 0; p < 4; ++p) {
            const int q = qq + 16 * p;
            const int j = (jw << 6) + q;
            float4 s = {0.f, 0.f, 0.f, 0.f};
            if (j >= i) {
                s = *(const float4*)(pw1 + ((size_t)i * 256 + j) * P_HID + n0 + 4 * c);
                if (j > i) {
                    const float4 bv = *(const float4*)(pw1 + ((size_t)j * 256 + i) * P_HID + n0 + 4 * c);
                    s.x += bv.x; s.y += bv.y; s.z += bv.z; s.w += bv.w;
                }
            }
            float* dst = &smem[q * 65 + 4 * c];
            dst[0] = s.x; dst[1] = s.y; dst[2] = s.z; dst[3] = s.w;
        }
        __syncthreads();

        const int e = tid & 7, nn = tid >> 3;    // k-chunk, n-row
#pragma unroll
        for (int p2 = 0; p2 < 2; ++p2) {
            const int n = nn + 32 * p2;
            half8 o;
#pragma unroll
            for (int q2 = 0; q2 < 8; ++q2)
                o[q2] = (_Float16)smem[(8 * e + q2) * 65 + n];
            *(half8*)(St + (size_t)(n0 + n) * K_PAD + (size_t)u * 64 + 8 * e) = o;
        }
    } else {
        // ---- concat build: 4 batch rows per block, one wave per row ----
        const int wv = tid >> 6, t = tid & 63;
        const int b = (blockIdx.x - PREP_BLOCKS) * 4 + wv;
        float* xs   = smem + wv * 13;
        float* bufA = smem + 64  + wv * 64;
        float* bufB = smem + 320 + wv * 64;

        if (t < 13) xs[t] = dense[b * 13 + t];
        __syncthreads();

        float h = db1[t];
#pragma unroll
        for (int d = 0; d < 13; ++d) h += xs[d] * dw1[d * 64 + t];
        bufA[t] = fmaxf(h, 0.f);
        __syncthreads();

        if (t < 32) {
            float o = db2[t];
#pragma unroll
            for (int k = 0; k < 64; ++k) o += bufA[k] * dw2[k * 32 + t];
            cbf[b * 256 + t] = (_Float16)o;
        }

        for (int f = 0; f < NFEAT; ++f) {
            __syncthreads();
            const int idx = sparse[b * NFEAT + f];
            bufB[t] = emb[((size_t)(f * CARD + idx)) * 64 + t];
            __syncthreads();
            float s = sb1[f * 64 + t];
#pragma unroll
            for (int e = 0; e < 64; ++e) s += bufB[e] * sw1[(f * 64 + e) * 64 + t];
            bufA[t] = fmaxf(s, 0.f);
            __syncthreads();
            if (t < 32) {
                float o = sb2[f * 32 + t];
#pragma unroll
                for (int k = 0; k < 64; ++k) o += bufA[k] * sw2[(f * 64 + k) * 32 + t];
                cbf[b * 256 + 32 + f * 32 + t] = (_Float16)o;
            }
        }
    }
}

// ---------------------------------------------------------------------------
// Kernel 2: hidden[b,n] = sum over packed pairs A[b,k] * St[n,k].
// fp16 GEMM M=2048 N=512 K=40960; A[b,q] = c[b,i] * c[b,jw*64+q] per unit —
// scalar broadcast x ALIGNED window. B via global_load_lds, XOR-swizzled.
// ---------------------------------------------------------------------------
__global__ __launch_bounds__(256, 4) void bilinear_gemm(
    const _Float16* __restrict__ cbf, const _Float16* __restrict__ St,
    _Float16* __restrict__ hidpart)
{
    __shared__ _Float16 Al[BM][BK + 8];   // 144 B stride -> uniform banks
    __shared__ _Float16 Bl[BN][BK];       // packed 128 B rows, XOR-swizzled

    // XCD-aware decode: 16 m-blocks of one (nt,ks) slice share one XCD's L2.
    const int b = blockIdx.x;
    const int xcd = b & 7, slot = b >> 3;
    const int mt = slot & 15;
    const int slice = ((slot >> 4) << 3) | xcd;
    const int nt = slice & 3, ks = slice >> 2;
    const int m0 = mt * BM, n0 = nt * BN;
    const int t0 = ks * TILES_PER_SPLIT;

    const int tid = threadIdx.x, lane = tid & 63, wv = tid >> 6;
    const int wrow = (wv & 1) * 64, wcol = (wv >> 1) * 64;
    const int arow = tid >> 1, ajoff = (tid & 1) * 32;  // A-gen: 2 thr/row

    floatx4 acc[4][4];
#pragma unroll
    for (int i = 0; i < 4; ++i)
#pragma unroll
        for (int j = 0; j < 4; ++j) acc[i][j] = (floatx4){0.f, 0.f, 0.f, 0.f};

    const _Float16* crow = cbf + (m0 + arow) * 256;
    const int drow = wv * 32 + (lane >> 3);
    const int eswz = (lane & 7) ^ ((lane >> 3) & 7);
    const _Float16* bsrc = St + (size_t)(n0 + drow) * K_PAD + (size_t)t0 * 64 + eswz * 8;
    _Float16* bdst = &Bl[wv * 32][0];   // wave-uniform; HW adds lane*16B

    for (int it = 0; it < TILES_PER_SPLIT; ++it) {
        // ---- B stage: async DMA, 4 x 1KB issues per wave ----
#pragma unroll
        for (int p = 0; p < 4; ++p)
            dma16(bsrc + (size_t)(p * 8) * K_PAD, bdst + (p * 8) * BK);
        bsrc += BK;

        // ---- A-gen: scalar x aligned window (overlaps DMA) ----
        int ui, ujw;
        unit_decode(t0 + it, ui, ujw);
        const _Float16 ci = crow[ui];
        const half8 civ = {ci, ci, ci, ci, ci, ci, ci, ci};
        const _Float16* cj = crow + (ujw << 6) + ajoff;   // 16B-aligned
#pragma unroll
        for (int x = 0; x < 32; x += 8) {
            half8 v = *(const half8*)(cj + x);
            *(half8*)&Al[arow][ajoff + x] = v * civ;      // 4x v_pk_mul_f16
        }
        __syncthreads();   // drains vmcnt (DMA) + lgkm (A writes)

        // ---- MFMA: 2 k-steps of 32, 4x4 16x16 tiles per wave ----
#pragma unroll
        for (int kk = 0; kk < BK; kk += 32) {
            half8 af[4], bfr[4];
#pragma unroll
            for (int i = 0; i < 4; ++i)
                af[i] = *(const half8*)&Al[wrow + i * 16 + (lane & 15)][kk + (lane >> 4) * 8];
#pragma unroll
            for (int j = 0; j < 4; ++j) {
                const int s = (((kk >> 3) + (lane >> 4)) ^ (lane & 7)) * 8;
                bfr[j] = *(const half8*)&Bl[wcol + j * 16 + (lane & 15)][s];
            }
#pragma unroll
            for (int i = 0; i < 4; ++i)
#pragma unroll
                for (int j = 0; j < 4; ++j)
                    acc[i][j] = __builtin_amdgcn_mfma_f32_16x16x32_f16(
                        af[i], bfr[j], acc[i][j], 0, 0, 0);
        }
        __syncthreads();
    }

    // epilogue: C/D layout col=lane&15, row=(lane>>4)*4+r (m89-verified)
    _Float16* outp = hidpart + (size_t)ks * BATCH * P_HID;
    const int r0 = m0 + wrow + (lane >> 4) * 4;
    const int c0 = n0 + wcol + (lane & 15);
#pragma unroll
    for (int i = 0; i < 4; ++i)
#pragma unroll
        for (int j = 0; j < 4; ++j)
#pragma unroll
            for (int r = 0; r < 4; ++r)
                outp[(size_t)(r0 + i * 16 + r) * P_HID + c0 + j * 16] =
                    (_Float16)acc[i][j][r];
}

// ---------------------------------------------------------------------------
// Kernel 3: sum k-splits + pb1, ReLU, dot with pw2, +pb2, sigmoid -> f32 out
// ---------------------------------------------------------------------------
__global__ void finalize(const _Float16* __restrict__ hidpart,
                         const float* __restrict__ pb1,
                         const float* __restrict__ pw2,
                         const float* __restrict__ pb2,
                         float* __restrict__ out)
{
    const int b = blockIdx.x, t = threadIdx.x;  // 256 threads
    float accv = 0.f;
#pragma unroll
    for (int h = 0; h < 2; ++h) {
        const int n = t + h * 256;
        float v = 0.f;
#pragma unroll
        for (int s = 0; s < KSPLIT; ++s)
            v += (float)hidpart[(size_t)s * BATCH * P_HID + (size_t)b * P_HID + n];
        v += pb1[n];
        v = fmaxf(v, 0.f);
        accv += v * pw2[n];
    }
#pragma unroll
    for (int off = 32; off; off >>= 1) accv += __shfl_down(accv, off, 64);
    __shared__ float red[4];
    const int lane = t & 63, wv = t >> 6;
    if (lane == 0) red[wv] = accv;
    __syncthreads();
    if (t == 0) {
        const float s = red[0] + red[1] + red[2] + red[3] + pb2[0];
        out[b] = 1.f / (1.f + expf(-s));
    }
}

extern "C" void kernel_launch(void* const* d_in, const int* in_sizes, int n_in,
                              void* d_out, int out_size, void* d_ws, size_t ws_size,
                              hipStream_t stream)
{
    const float* dense  = (const float*)d_in[0];
    const int*   sparse = (const int*)d_in[1];
    // d_in[2] tokenizers == arange(CARD): gather index is the sparse value itself
    const float* emb = (const float*)d_in[3];
    const float* dw1 = (const float*)d_in[4];
    const float* db1 = (const float*)d_in[5];
    const float* dw2 = (const float*)d_in[6];
    const float* db2 = (const float*)d_in[7];
    const float* sw1 = (const float*)d_in[8];
    const float* sb1 = (const float*)d_in[9];
    const float* sw2 = (const float*)d_in[10];
    const float* sb2 = (const float*)d_in[11];
    const float* pw1 = (const float*)d_in[12];
    const float* pb1 = (const float*)d_in[13];
    const float* pw2 = (const float*)d_in[14];
    const float* pb2 = (const float*)d_in[15];

    char* ws = (char*)d_ws;
    _Float16* cbf     = (_Float16*)ws;                                   // 1 MB
    _Float16* St      = (_Float16*)(ws + (1 << 20));                     // 40 MB
    _Float16* hidpart = (_Float16*)(ws + (1 << 20) + ((size_t)40 << 20)); // 32 MB

    fused_pre<<<PREP_BLOCKS + BATCH / 4, 256, 0, stream>>>(
        dense, sparse, emb, dw1, db1, dw2, db2, sw1, sb1, sw2, sb2, pw1,
        cbf, St);
    bilinear_gemm<<<16 * 4 * KSPLIT, 256, 0, stream>>>(cbf, St, hidpart);
    finalize<<<BATCH, 256, 0, stream>>>(hidpart, pb1, pw2, pb2, (float*)d_out);
}